// Round 7
// baseline (372.328 us; speedup 1.0000x reference)
//
#include <hip/hip_runtime.h>
#include <hip/hip_bf16.h>

// B=8, N=2048, Q=256, D=1024, H=16, HD=64 cross-attention.
// R7: attention restructured. scores_exp: single-shot BK=64 GEMM (1 barrier),
// fused exp + atomic row-sum l. pv: split-K=4, 256x64 tiles (MT=8), raw fp32
// partials. reduce: sum partials / global l. l zero-init in cast kernel.
// Proj keeps R5's packed vT store (127 us, m97-plateau).

typedef unsigned short u16;
typedef __attribute__((ext_vector_type(8))) short short8;   // 8 bf16 = 4 VGPR
typedef __attribute__((ext_vector_type(4))) float floatx4;  // MFMA acc

static_assert(sizeof(short8) == 16, "short8 must be 16B");

__device__ __forceinline__ u16 f2bf(float f) {
  unsigned int x = __float_as_uint(f);
  x += 0x7fffu + ((x >> 16) & 1u);   // RNE
  return (u16)(x >> 16);
}

// async global->LDS, 16 B per lane; lds = wave-uniform base, lane i -> base+i*16
__device__ __forceinline__ void gload16(const u16* g, u16* lds) {
  __builtin_amdgcn_global_load_lds(
      (const __attribute__((address_space(1))) unsigned int*)g,
      (__attribute__((address_space(3))) unsigned int*)lds, 16, 0, 0);
}

// ------------- fused fp32->bf16 cast over all 4 inputs + zero lsum -------------
__global__ __launch_bounds__(256) void f2bf_multi(
    const float* __restrict__ s, u16* __restrict__ so,
    const float* __restrict__ q, u16* __restrict__ qo,
    const float* __restrict__ wi, u16* __restrict__ wio,
    const float* __restrict__ wo, u16* __restrict__ woo,
    float* __restrict__ lsum) {
  int i = blockIdx.x * 256 + threadIdx.x;
  const float* in; u16* out; int idx;
  if (i < 4194304)      { in = s;  out = so;  idx = i; }
  else if (i < 4718592) { in = q;  out = qo;  idx = i - 4194304; }
  else if (i < 5505024) { in = wi; out = wio; idx = i - 4718592; }
  else if (i < 5767168) { in = wo; out = woo; idx = i - 5505024; }
  else if (i < 5775360) {               // zero the 32768-float l buffer
    float4 z4 = {0.f, 0.f, 0.f, 0.f};
    reinterpret_cast<float4*>(lsum)[i - 5767168] = z4;
    return;
  } else return;
  float4 v = reinterpret_cast<const float4*>(in)[idx];
  ushort4 o;
  o.x = f2bf(v.x); o.y = f2bf(v.y); o.z = f2bf(v.z); o.w = f2bf(v.w);
  reinterpret_cast<ushort4*>(out)[idx] = o;
}

// ---------------- LDS-staged GEMM core: tile (MT*32) x (NT*32), BK=32 ----------------
template <int MT, int NT>
__device__ __forceinline__ void gemm_core(
    const u16* __restrict__ A, int lda,
    const u16* __restrict__ Bm, int ldb, int K,
    u16* __restrict__ Alds, u16* __restrict__ Blds,
    floatx4 (&acc)[MT][NT]) {
  const int t = threadIdx.x;
  const int wave = t >> 6, lane = t & 63;
  const int rr = lane & 15, kq = lane >> 4;
  constexpr int AI = (MT * 128) / 256;
  constexpr int BI = (NT * 128) / 256;

  const u16* ag[AI]; u16* al[AI];
#pragma unroll
  for (int i = 0; i < AI; ++i) {
    int s = i * 256 + t;
    ag[i] = A + (size_t)(s >> 2) * lda + (s & 3) * 8;
    al[i] = Alds + (size_t)(i * 256 + wave * 64) * 8;
  }
  const u16* bg[BI]; u16* bl[BI];
#pragma unroll
  for (int i = 0; i < BI; ++i) {
    int s = i * 256 + t;
    bg[i] = Bm + (size_t)(s >> 2) * ldb + (s & 3) * 8;
    bl[i] = Blds + (size_t)(i * 256 + wave * 64) * 8;
  }

  const int m0w = (wave & 1) * (MT * 16);
  const int n0w = (wave >> 1) * (NT * 16);
  const u16* ar[MT];
  const u16* br[NT];
#pragma unroll
  for (int mi = 0; mi < MT; ++mi)
    ar[mi] = Alds + (size_t)(m0w + mi * 16 + rr) * 32 + kq * 8;
#pragma unroll
  for (int ni = 0; ni < NT; ++ni)
    br[ni] = Blds + (size_t)(n0w + ni * 16 + rr) * 32 + kq * 8;

  for (int k0 = 0; k0 < K; k0 += 32) {
#pragma unroll
    for (int i = 0; i < AI; ++i) gload16(ag[i] + k0, al[i]);
#pragma unroll
    for (int i = 0; i < BI; ++i) gload16(bg[i] + k0, bl[i]);
    __syncthreads();
    short8 af[MT], bfr[NT];
#pragma unroll
    for (int mi = 0; mi < MT; ++mi) af[mi] = *reinterpret_cast<const short8*>(ar[mi]);
#pragma unroll
    for (int ni = 0; ni < NT; ++ni) bfr[ni] = *reinterpret_cast<const short8*>(br[ni]);
#pragma unroll
    for (int mi = 0; mi < MT; ++mi)
#pragma unroll
      for (int ni = 0; ni < NT; ++ni)
        acc[mi][ni] = __builtin_amdgcn_mfma_f32_16x16x32_bf16(af[mi], bfr[ni], acc[mi][ni], 0, 0, 0);
    __syncthreads();
  }
}

// ---- unified projection: y<128 -> K/V (N=2048, V transposed), y>=128 -> Q ----
__global__ __launch_bounds__(256) void gemm_proj(
    const u16* __restrict__ s_bf, const u16* __restrict__ qy_bf,
    const u16* __restrict__ wi_bf, const float* __restrict__ b_in,
    u16* __restrict__ kp, u16* __restrict__ vT, u16* __restrict__ qp) {
  __shared__ u16 Alds[128 * 32];
  __shared__ u16 Blds[128 * 32];
  const int by = blockIdx.y, bx = blockIdx.x;
  const bool isq = (by >= 128);
  if (isq && bx >= 8) return;      // Q has N=1024 only
  const int mB = (isq ? by - 128 : by) * 128;
  const int nB = bx * 128;
  const u16* A = (isq ? qy_bf : s_bf) + (size_t)mB * 1024;
  const u16* W = wi_bf + (size_t)(isq ? nB : 1024 + nB) * 1024;
  const float* bias = b_in + (isq ? nB : 1024 + nB);

  const floatx4 zz = {0.f, 0.f, 0.f, 0.f};
  floatx4 acc[4][4] = {{zz, zz, zz, zz}, {zz, zz, zz, zz}, {zz, zz, zz, zz}, {zz, zz, zz, zz}};
  gemm_core<4, 4>(A, 1024, W, 1024, 1024, Alds, Blds, acc);

  const int lane = threadIdx.x & 63, wave = threadIdx.x >> 6;
  const int rr = lane & 15, r4 = (lane >> 4) * 4;
  const int m0w = (wave & 1) * 64, n0w = (wave >> 1) * 64;

  if (isq) {
#pragma unroll
    for (int mi = 0; mi < 4; ++mi)
#pragma unroll
      for (int ni = 0; ni < 4; ++ni) {
        int nl = n0w + ni * 16 + rr;
        float bv = bias[nl];
#pragma unroll
        for (int r = 0; r < 4; ++r) {
          int m = mB + m0w + mi * 16 + r4 + r;
          qp[(size_t)m * 1024 + nB + nl] = f2bf((acc[mi][ni][r] + bv) * 0.125f);
        }
      }
  } else if (nB < 1024) {
#pragma unroll
    for (int mi = 0; mi < 4; ++mi)
#pragma unroll
      for (int ni = 0; ni < 4; ++ni) {
        int nl = n0w + ni * 16 + rr;
        float bv = bias[nl];
#pragma unroll
        for (int r = 0; r < 4; ++r) {
          int m = mB + m0w + mi * 16 + r4 + r;
          kp[(size_t)m * 1024 + nB + nl] = f2bf(acc[mi][ni][r] + bv);
        }
      }
  } else {
    // V: packed transposed store, 4 m-rows (j-consecutive) per ushort4
#pragma unroll
    for (int mi = 0; mi < 4; ++mi)
#pragma unroll
      for (int ni = 0; ni < 4; ++ni) {
        int n2 = nB + n0w + ni * 16 + rr - 1024;
        int h = n2 >> 6, d = n2 & 63;
        float bv = bias[n0w + ni * 16 + rr];
        int m0 = mB + m0w + mi * 16 + r4;      // 4 consecutive rows, same b
        int b = m0 >> 11, j0 = m0 & 2047;
        ushort4 o;
        o.x = f2bf(acc[mi][ni][0] + bv);
        o.y = f2bf(acc[mi][ni][1] + bv);
        o.z = f2bf(acc[mi][ni][2] + bv);
        o.w = f2bf(acc[mi][ni][3] + bv);
        *reinterpret_cast<ushort4*>(
            vT + ((size_t)(b * 16 + h) * 64 + d) * 2048 + j0) = o;
      }
  }
}

// ---- scores+exp single-shot: P = exp(q_h . k_h), BK=64, one barrier ----
// Also accumulates row-sums l[bh][q] via shfl-reduce + atomicAdd.
__global__ __launch_bounds__(256) void gemm_scores_exp(
    const u16* __restrict__ qp, const u16* __restrict__ kp,
    u16* __restrict__ sc, float* __restrict__ lsum, int b0) {
  __shared__ u16 Alds[128 * 64];   // 16 KB
  __shared__ u16 Blds[128 * 64];   // 16 KB
  const int t = threadIdx.x;
  const int wave = t >> 6, lane = t & 63;
  const int rr = lane & 15, kq = lane >> 4;
  const int bz = blockIdx.z, bl = bz >> 4, h = bz & 15;
  const int b = b0 + bl;
  const int mB = blockIdx.y * 128;
  const int nB = blockIdx.x * 128;
  const u16* A = qp + (size_t)(b * 256 + mB) * 1024 + h * 64;
  const u16* Bm = kp + (size_t)(b * 2048 + nB) * 1024 + h * 64;
  u16* C = sc + (size_t)bz * 256 * 2048;

  // stage whole 128x64 A and B tiles (slot s -> row s>>3, col8 s&7)
#pragma unroll
  for (int i = 0; i < 4; ++i) {
    int s = i * 256 + t;
    gload16(A + (size_t)(s >> 3) * 1024 + (s & 7) * 8,
            Alds + (size_t)(i * 256 + wave * 64) * 8);
  }
#pragma unroll
  for (int i = 0; i < 4; ++i) {
    int s = i * 256 + t;
    gload16(Bm + (size_t)(s >> 3) * 1024 + (s & 7) * 8,
            Blds + (size_t)(i * 256 + wave * 64) * 8);
  }
  __syncthreads();

  const int m0w = (wave & 1) * 64, n0w = (wave >> 1) * 64;
  const floatx4 zz = {0.f, 0.f, 0.f, 0.f};
  floatx4 acc[4][4] = {{zz, zz, zz, zz}, {zz, zz, zz, zz}, {zz, zz, zz, zz}, {zz, zz, zz, zz}};
#pragma unroll
  for (int ki = 0; ki < 2; ++ki) {
    short8 af[4], bfr[4];
#pragma unroll
    for (int mi = 0; mi < 4; ++mi)
      af[mi] = *reinterpret_cast<const short8*>(
          Alds + (size_t)(m0w + mi * 16 + rr) * 64 + ki * 32 + kq * 8);
#pragma unroll
    for (int ni = 0; ni < 4; ++ni)
      bfr[ni] = *reinterpret_cast<const short8*>(
          Blds + (size_t)(n0w + ni * 16 + rr) * 64 + ki * 32 + kq * 8);
#pragma unroll
    for (int mi = 0; mi < 4; ++mi)
#pragma unroll
      for (int ni = 0; ni < 4; ++ni)
        acc[mi][ni] = __builtin_amdgcn_mfma_f32_16x16x32_bf16(af[mi], bfr[ni], acc[mi][ni], 0, 0, 0);
  }

  // epilogue: e = exp(s); store bf16 P; row-sum over this tile -> atomicAdd l
#pragma unroll
  for (int mi = 0; mi < 4; ++mi)
#pragma unroll
    for (int r = 0; r < 4; ++r) {
      float rsum = 0.f;
#pragma unroll
      for (int ni = 0; ni < 4; ++ni) {
        float e = __expf(acc[mi][ni][r]);
        int m = mB + m0w + mi * 16 + kq * 4 + r;
        int n = nB + n0w + ni * 16 + rr;
        C[(size_t)m * 2048 + n] = f2bf(e);
        rsum += e;
      }
      rsum += __shfl_xor(rsum, 1, 64);
      rsum += __shfl_xor(rsum, 2, 64);
      rsum += __shfl_xor(rsum, 4, 64);
      rsum += __shfl_xor(rsum, 8, 64);
      if (rr == 0) {
        int m = mB + m0w + mi * 16 + kq * 4 + r;
        atomicAdd(&lsum[(size_t)(b * 16 + h) * 256 + m], rsum);
      }
    }
}

// ---- PV split-K=4: 256x64 tile (MT=8,NT=2), raw fp32 partials ----
__global__ __launch_bounds__(256) void gemm_pv(
    const u16* __restrict__ sc, const u16* __restrict__ vT,
    float* __restrict__ po, int b0, int nbh) {
  __shared__ u16 Alds[256 * 32];   // 16 KB
  __shared__ u16 Blds[64 * 32];    // 4 KB
  const int t = threadIdx.x;
  const int wave = t >> 6, lane = t & 63;
  const int rr = lane & 15, kq = lane >> 4;
  const int z = blockIdx.x, bhl = blockIdx.z;
  const int bl = bhl >> 4, h = bhl & 15;
  const int b = b0 + bl;
  const u16* A = sc + (size_t)bhl * 256 * 2048 + z * 512;
  const u16* Bm = vT + (size_t)(b * 16 + h) * 64 * 2048 + z * 512;

  const u16* ag[4]; u16* al[4];
#pragma unroll
  for (int i = 0; i < 4; ++i) {
    int s = i * 256 + t;
    ag[i] = A + (size_t)(s >> 2) * 2048 + (s & 3) * 8;
    al[i] = Alds + (size_t)(i * 256 + wave * 64) * 8;
  }
  const u16* bg = Bm + (size_t)(t >> 2) * 2048 + (t & 3) * 8;
  u16* blp = Blds + (size_t)(wave * 64) * 8;

  const int m0w = (wave & 1) * 128, n0w = (wave >> 1) * 32;
  const u16* ar[8];
  const u16* br[2];
#pragma unroll
  for (int mi = 0; mi < 8; ++mi)
    ar[mi] = Alds + (size_t)(m0w + mi * 16 + rr) * 32 + kq * 8;
#pragma unroll
  for (int ni = 0; ni < 2; ++ni)
    br[ni] = Blds + (size_t)(n0w + ni * 16 + rr) * 32 + kq * 8;

  const floatx4 zz = {0.f, 0.f, 0.f, 0.f};
  floatx4 acc[8][2] = {{zz, zz}, {zz, zz}, {zz, zz}, {zz, zz},
                       {zz, zz}, {zz, zz}, {zz, zz}, {zz, zz}};

  for (int k0 = 0; k0 < 512; k0 += 32) {
#pragma unroll
    for (int i = 0; i < 4; ++i) gload16(ag[i] + k0, al[i]);
    gload16(bg + k0, blp);
    __syncthreads();
    short8 af[8], bfr[2];
#pragma unroll
    for (int mi = 0; mi < 8; ++mi) af[mi] = *reinterpret_cast<const short8*>(ar[mi]);
#pragma unroll
    for (int ni = 0; ni < 2; ++ni) bfr[ni] = *reinterpret_cast<const short8*>(br[ni]);
#pragma unroll
    for (int mi = 0; mi < 8; ++mi)
#pragma unroll
      for (int ni = 0; ni < 2; ++ni)
        acc[mi][ni] = __builtin_amdgcn_mfma_f32_16x16x32_bf16(af[mi], bfr[ni], acc[mi][ni], 0, 0, 0);
    __syncthreads();
  }

  // store raw partials: po[z][bhl][q][d]
  float* pob = po + ((size_t)(z * nbh + bhl) * 256) * 64;
#pragma unroll
  for (int mi = 0; mi < 8; ++mi)
#pragma unroll
    for (int r = 0; r < 4; ++r) {
      int m = m0w + mi * 16 + kq * 4 + r;
#pragma unroll
      for (int ni = 0; ni < 2; ++ni)
        pob[(size_t)m * 64 + n0w + ni * 16 + rr] = acc[mi][ni][r];
    }
}

// ---- reduce: ao = (sum_z po)/l, bf16 ----
__global__ __launch_bounds__(256) void attn_reduce(
    const float* __restrict__ po, const float* __restrict__ lsum,
    u16* __restrict__ ao, int b0, int nb) {
  int i = blockIdx.x * 256 + threadIdx.x;     // float4 group over [bhl][q][64]
  int d4 = i & 15, q = (i >> 4) & 255, bhl = i >> 12;
  int h = bhl & 15, b = b0 + (bhl >> 4);
  const int poz = nb * 16 * 256 * 16;         // z-stride in float4 units
  float inv = 1.0f / lsum[(size_t)(b * 16 + h) * 256 + q];
  const float4* p4 = reinterpret_cast<const float4*>(po);
  float4 s = p4[i];
  float4 s1 = p4[poz + i];
  float4 s2 = p4[2 * poz + i];
  float4 s3 = p4[3 * poz + i];
  s.x += s1.x + s2.x + s3.x;
  s.y += s1.y + s2.y + s3.y;
  s.z += s1.z + s2.z + s3.z;
  s.w += s1.w + s2.w + s3.w;
  ushort4 o;
  o.x = f2bf(s.x * inv); o.y = f2bf(s.y * inv);
  o.z = f2bf(s.z * inv); o.w = f2bf(s.w * inv);
  reinterpret_cast<ushort4*>(ao)[(size_t)(b * 256 + q) * 256 + h * 16 + d4] = o;
}

// ---- out-proj: out = ao @ w_out^T + b_out + queries (fp32), 64x128 tiles ----
__global__ __launch_bounds__(256) void gemm_out(
    const u16* __restrict__ A, const u16* __restrict__ W,
    const float* __restrict__ bias, const float* __restrict__ resid,
    float* __restrict__ out) {
  __shared__ u16 Alds[64 * 32];
  __shared__ u16 Blds[128 * 32];
  const int mB = blockIdx.y * 64;
  const int nB = blockIdx.x * 128;
  const floatx4 zz = {0.f, 0.f, 0.f, 0.f};
  floatx4 acc[2][4] = {{zz, zz, zz, zz}, {zz, zz, zz, zz}};
  gemm_core<2, 4>(A + (size_t)mB * 1024, 1024, W + (size_t)nB * 1024, 1024, 1024,
                  Alds, Blds, acc);
  const int lane = threadIdx.x & 63, wave = threadIdx.x >> 6;
  const int rr = lane & 15, r4 = (lane >> 4) * 4;
  const int m0w = (wave & 1) * 32, n0w = (wave >> 1) * 64;
#pragma unroll
  for (int mi = 0; mi < 2; ++mi)
#pragma unroll
    for (int ni = 0; ni < 4; ++ni) {
      int n = nB + n0w + ni * 16 + rr;
      float bv = bias[n];
#pragma unroll
      for (int r = 0; r < 4; ++r) {
        int m = mB + m0w + mi * 16 + r4 + r;
        size_t idx = (size_t)m * 1024 + n;
        out[idx] = acc[mi][ni][r] + bv + resid[idx];
      }
    }
}

extern "C" void kernel_launch(void* const* d_in, const int* in_sizes, int n_in,
                              void* d_out, int out_size, void* d_ws, size_t ws_size,
                              hipStream_t stream) {
  const float* sources = (const float*)d_in[0];  // [8,2048,1024]
  const float* queries = (const float*)d_in[1];  // [8,256,1024]
  const float* w_in    = (const float*)d_in[2];  // [3072,1024]
  const float* b_in    = (const float*)d_in[3];  // [3072]
  const float* w_out   = (const float*)d_in[4];  // [1024,1024]
  const float* b_out   = (const float*)d_in[5];  // [1024]
  float* out = (float*)d_out;                    // [8,256,1024] fp32

  char* ws = (char*)d_ws;
  size_t off = 0;
  auto alloc = [&](size_t bytes) -> char* {
    char* p = ws + off;
    off += bytes;
    off = (off + 255) & ~(size_t)255;
    return p;
  };
  u16* s_bf  = (u16*)alloc((size_t)16777216 * 2);  // sources bf16
  u16* qy_bf = (u16*)alloc((size_t)2097152 * 2);   // queries bf16
  u16* wi_bf = (u16*)alloc((size_t)3145728 * 2);   // w_in bf16
  u16* wo_bf = (u16*)alloc((size_t)1048576 * 2);   // w_out bf16
  u16* qp    = (u16*)alloc((size_t)2097152 * 2);   // projected q (pre-scaled 1/8)
  u16* kp    = (u16*)alloc((size_t)16777216 * 2);  // projected k
  u16* vT    = (u16*)alloc((size_t)16777216 * 2);  // projected v, [bh][d][n]
  u16* ao    = (u16*)alloc((size_t)2097152 * 2);   // attention output
  float* lsum = (float*)alloc((size_t)32768 * 4);  // softmax denominators
  float* po   = (float*)alloc((size_t)4 * 2097152 * 4);  // split-K partials (32 MB)
  // P buffer: 16.8 MB per batch element; chunk over batch to fit ws
  const size_t sc_bytes_per_b = (size_t)16 * 256 * 2048 * 2;
  size_t remain = ws_size > off ? ws_size - off : 0;
  int bchunk = (int)(remain / sc_bytes_per_b);
  if (bchunk > 8) bchunk = 8;
  if (bchunk < 1) bchunk = 1;
  u16* sc = (u16*)(ws + off);

  // 1) casts + lsum zero-init (single kernel)
  f2bf_multi<<<dim3(22560), 256, 0, stream>>>(
      sources, s_bf, queries, qy_bf, w_in, wi_bf, w_out, wo_bf, lsum);

  // 2) unified QKV projection
  gemm_proj<<<dim3(16, 144), 256, 0, stream>>>(
      s_bf, qy_bf, wi_bf, b_in, kp, vT, qp);

  // 3) attention: P = exp(QK^T) (+l via atomics), split-K PV, reduce
  for (int b0 = 0; b0 < 8; b0 += bchunk) {
    int nb = (8 - b0) < bchunk ? (8 - b0) : bchunk;
    gemm_scores_exp<<<dim3(16, 2, nb * 16), 256, 0, stream>>>(qp, kp, sc, lsum, b0);
    gemm_pv<<<dim3(4, 1, nb * 16), 256, 0, stream>>>(sc, vT, po, b0, nb * 16);
    attn_reduce<<<dim3(nb * 256), 256, 0, stream>>>(po, lsum, ao, b0, nb);
  }

  // 4) out-proj + bias + residual
  gemm_out<<<dim3(8, 32), 256, 0, stream>>>(ao, wo_bf, b_out, queries, out);
}

// Round 8
// 340.165 us; speedup vs baseline: 1.0946x; 1.0946x over previous
//
#include <hip/hip_runtime.h>
#include <hip/hip_bf16.h>

// B=8, N=2048, Q=256, D=1024, H=16, HD=64 cross-attention.
// R8 = R6 base + (a) sc overlaps dead cast buffers (live set 74 MB -> better
// batch chunking), (b) single-shot BK=64 scores_exp (1 barrier, no atomics),
// (c) PV with BK=64 staging (half the barriers) + ones-column l (no reduce).

typedef unsigned short u16;
typedef __attribute__((ext_vector_type(8))) short short8;   // 8 bf16 = 4 VGPR
typedef __attribute__((ext_vector_type(4))) float floatx4;  // MFMA acc

static_assert(sizeof(short8) == 16, "short8 must be 16B");

__device__ __forceinline__ u16 f2bf(float f) {
  unsigned int x = __float_as_uint(f);
  x += 0x7fffu + ((x >> 16) & 1u);   // RNE
  return (u16)(x >> 16);
}

// async global->LDS, 16 B per lane; lds = wave-uniform base, lane i -> base+i*16
__device__ __forceinline__ void gload16(const u16* g, u16* lds) {
  __builtin_amdgcn_global_load_lds(
      (const __attribute__((address_space(1))) unsigned int*)g,
      (__attribute__((address_space(3))) unsigned int*)lds, 16, 0, 0);
}

// ------------- fused fp32->bf16 cast over all 4 inputs -------------
__global__ __launch_bounds__(256) void f2bf_multi(
    const float* __restrict__ s, u16* __restrict__ so,
    const float* __restrict__ q, u16* __restrict__ qo,
    const float* __restrict__ wi, u16* __restrict__ wio,
    const float* __restrict__ wo, u16* __restrict__ woo) {
  int i = blockIdx.x * 256 + threadIdx.x;
  const float* in; u16* out; int idx;
  if (i < 4194304)      { in = s;  out = so;  idx = i; }
  else if (i < 4718592) { in = q;  out = qo;  idx = i - 4194304; }
  else if (i < 5505024) { in = wi; out = wio; idx = i - 4718592; }
  else if (i < 5767168) { in = wo; out = woo; idx = i - 5505024; }
  else return;
  float4 v = reinterpret_cast<const float4*>(in)[idx];
  ushort4 o;
  o.x = f2bf(v.x); o.y = f2bf(v.y); o.z = f2bf(v.z); o.w = f2bf(v.w);
  reinterpret_cast<ushort4*>(out)[idx] = o;
}

// ---------------- LDS-staged GEMM core: tile (MT*32) x (NT*32), BK=32 ----------------
template <int MT, int NT>
__device__ __forceinline__ void gemm_core(
    const u16* __restrict__ A, int lda,
    const u16* __restrict__ Bm, int ldb, int K,
    u16* __restrict__ Alds, u16* __restrict__ Blds,
    floatx4 (&acc)[MT][NT]) {
  const int t = threadIdx.x;
  const int wave = t >> 6, lane = t & 63;
  const int rr = lane & 15, kq = lane >> 4;
  constexpr int AI = (MT * 128) / 256;
  constexpr int BI = (NT * 128) / 256;

  const u16* ag[AI]; u16* al[AI];
#pragma unroll
  for (int i = 0; i < AI; ++i) {
    int s = i * 256 + t;
    ag[i] = A + (size_t)(s >> 2) * lda + (s & 3) * 8;
    al[i] = Alds + (size_t)(i * 256 + wave * 64) * 8;
  }
  const u16* bg[BI]; u16* bl[BI];
#pragma unroll
  for (int i = 0; i < BI; ++i) {
    int s = i * 256 + t;
    bg[i] = Bm + (size_t)(s >> 2) * ldb + (s & 3) * 8;
    bl[i] = Blds + (size_t)(i * 256 + wave * 64) * 8;
  }

  const int m0w = (wave & 1) * (MT * 16);
  const int n0w = (wave >> 1) * (NT * 16);
  const u16* ar[MT];
  const u16* br[NT];
#pragma unroll
  for (int mi = 0; mi < MT; ++mi)
    ar[mi] = Alds + (size_t)(m0w + mi * 16 + rr) * 32 + kq * 8;
#pragma unroll
  for (int ni = 0; ni < NT; ++ni)
    br[ni] = Blds + (size_t)(n0w + ni * 16 + rr) * 32 + kq * 8;

  for (int k0 = 0; k0 < K; k0 += 32) {
#pragma unroll
    for (int i = 0; i < AI; ++i) gload16(ag[i] + k0, al[i]);
#pragma unroll
    for (int i = 0; i < BI; ++i) gload16(bg[i] + k0, bl[i]);
    __syncthreads();
    short8 af[MT], bfr[NT];
#pragma unroll
    for (int mi = 0; mi < MT; ++mi) af[mi] = *reinterpret_cast<const short8*>(ar[mi]);
#pragma unroll
    for (int ni = 0; ni < NT; ++ni) bfr[ni] = *reinterpret_cast<const short8*>(br[ni]);
#pragma unroll
    for (int mi = 0; mi < MT; ++mi)
#pragma unroll
      for (int ni = 0; ni < NT; ++ni)
        acc[mi][ni] = __builtin_amdgcn_mfma_f32_16x16x32_bf16(af[mi], bfr[ni], acc[mi][ni], 0, 0, 0);
    __syncthreads();
  }
}

// ---- unified projection: y<128 -> K/V (N=2048, V transposed), y>=128 -> Q ----
__global__ __launch_bounds__(256) void gemm_proj(
    const u16* __restrict__ s_bf, const u16* __restrict__ qy_bf,
    const u16* __restrict__ wi_bf, const float* __restrict__ b_in,
    u16* __restrict__ kp, u16* __restrict__ vT, u16* __restrict__ qp) {
  __shared__ u16 Alds[128 * 32];
  __shared__ u16 Blds[128 * 32];
  const int by = blockIdx.y, bx = blockIdx.x;
  const bool isq = (by >= 128);
  if (isq && bx >= 8) return;      // Q has N=1024 only
  const int mB = (isq ? by - 128 : by) * 128;
  const int nB = bx * 128;
  const u16* A = (isq ? qy_bf : s_bf) + (size_t)mB * 1024;
  const u16* W = wi_bf + (size_t)(isq ? nB : 1024 + nB) * 1024;
  const float* bias = b_in + (isq ? nB : 1024 + nB);

  const floatx4 zz = {0.f, 0.f, 0.f, 0.f};
  floatx4 acc[4][4] = {{zz, zz, zz, zz}, {zz, zz, zz, zz}, {zz, zz, zz, zz}, {zz, zz, zz, zz}};
  gemm_core<4, 4>(A, 1024, W, 1024, 1024, Alds, Blds, acc);

  const int lane = threadIdx.x & 63, wave = threadIdx.x >> 6;
  const int rr = lane & 15, r4 = (lane >> 4) * 4;
  const int m0w = (wave & 1) * 64, n0w = (wave >> 1) * 64;

  if (isq) {
#pragma unroll
    for (int mi = 0; mi < 4; ++mi)
#pragma unroll
      for (int ni = 0; ni < 4; ++ni) {
        int nl = n0w + ni * 16 + rr;
        float bv = bias[nl];
#pragma unroll
        for (int r = 0; r < 4; ++r) {
          int m = mB + m0w + mi * 16 + r4 + r;
          qp[(size_t)m * 1024 + nB + nl] = f2bf((acc[mi][ni][r] + bv) * 0.125f);
        }
      }
  } else if (nB < 1024) {
#pragma unroll
    for (int mi = 0; mi < 4; ++mi)
#pragma unroll
      for (int ni = 0; ni < 4; ++ni) {
        int nl = n0w + ni * 16 + rr;
        float bv = bias[nl];
#pragma unroll
        for (int r = 0; r < 4; ++r) {
          int m = mB + m0w + mi * 16 + r4 + r;
          kp[(size_t)m * 1024 + nB + nl] = f2bf(acc[mi][ni][r] + bv);
        }
      }
  } else {
    // V: packed transposed store, 4 m-rows (j-consecutive) per ushort4
#pragma unroll
    for (int mi = 0; mi < 4; ++mi)
#pragma unroll
      for (int ni = 0; ni < 4; ++ni) {
        int n2 = nB + n0w + ni * 16 + rr - 1024;
        int h = n2 >> 6, d = n2 & 63;
        float bv = bias[n0w + ni * 16 + rr];
        int m0 = mB + m0w + mi * 16 + r4;      // 4 consecutive rows, same b
        int b = m0 >> 11, j0 = m0 & 2047;
        ushort4 o;
        o.x = f2bf(acc[mi][ni][0] + bv);
        o.y = f2bf(acc[mi][ni][1] + bv);
        o.z = f2bf(acc[mi][ni][2] + bv);
        o.w = f2bf(acc[mi][ni][3] + bv);
        *reinterpret_cast<ushort4*>(
            vT + ((size_t)(b * 16 + h) * 64 + d) * 2048 + j0) = o;
      }
  }
}

// ---- scores+exp single-shot: P = exp(q_h . k_h), BK=64, ONE barrier ----
__global__ __launch_bounds__(256) void gemm_scores_exp(
    const u16* __restrict__ qp, const u16* __restrict__ kp,
    u16* __restrict__ sc, int b0) {
  __shared__ u16 Alds[128 * 64];   // 16 KB
  __shared__ u16 Blds[128 * 64];   // 16 KB
  const int t = threadIdx.x;
  const int wave = t >> 6, lane = t & 63;
  const int rr = lane & 15, kq = lane >> 4;
  const int bz = blockIdx.z, bl = bz >> 4, h = bz & 15;
  const int b = b0 + bl;
  const int mB = blockIdx.y * 128;
  const int nB = blockIdx.x * 128;
  const u16* A = qp + (size_t)(b * 256 + mB) * 1024 + h * 64;
  const u16* Bm = kp + (size_t)(b * 2048 + nB) * 1024 + h * 64;
  u16* C = sc + (size_t)bz * 256 * 2048;

  // stage whole 128x64 A and B tiles (slot s -> row s>>3, col8 s&7)
#pragma unroll
  for (int i = 0; i < 4; ++i) {
    int s = i * 256 + t;
    gload16(A + (size_t)(s >> 3) * 1024 + (s & 7) * 8,
            Alds + (size_t)(i * 256 + wave * 64) * 8);
  }
#pragma unroll
  for (int i = 0; i < 4; ++i) {
    int s = i * 256 + t;
    gload16(Bm + (size_t)(s >> 3) * 1024 + (s & 7) * 8,
            Blds + (size_t)(i * 256 + wave * 64) * 8);
  }
  __syncthreads();

  const int m0w = (wave & 1) * 64, n0w = (wave >> 1) * 64;
  const floatx4 zz = {0.f, 0.f, 0.f, 0.f};
  floatx4 acc[4][4] = {{zz, zz, zz, zz}, {zz, zz, zz, zz}, {zz, zz, zz, zz}, {zz, zz, zz, zz}};
#pragma unroll
  for (int ki = 0; ki < 2; ++ki) {
    short8 af[4], bfr[4];
#pragma unroll
    for (int mi = 0; mi < 4; ++mi)
      af[mi] = *reinterpret_cast<const short8*>(
          Alds + (size_t)(m0w + mi * 16 + rr) * 64 + ki * 32 + kq * 8);
#pragma unroll
    for (int ni = 0; ni < 4; ++ni)
      bfr[ni] = *reinterpret_cast<const short8*>(
          Blds + (size_t)(n0w + ni * 16 + rr) * 64 + ki * 32 + kq * 8);
#pragma unroll
    for (int mi = 0; mi < 4; ++mi)
#pragma unroll
      for (int ni = 0; ni < 4; ++ni)
        acc[mi][ni] = __builtin_amdgcn_mfma_f32_16x16x32_bf16(af[mi], bfr[ni], acc[mi][ni], 0, 0, 0);
  }

  // epilogue: store P = exp(s) bf16
#pragma unroll
  for (int mi = 0; mi < 4; ++mi)
#pragma unroll
    for (int ni = 0; ni < 4; ++ni) {
      int n = nB + n0w + ni * 16 + rr;
#pragma unroll
      for (int r = 0; r < 4; ++r) {
        int m = mB + m0w + mi * 16 + kq * 4 + r;
        C[(size_t)m * 2048 + n] = f2bf(__expf(acc[mi][ni][r]));
      }
    }
}

// ---- PV + l: O = P @ V, l via constant ones B-frag; BK=64 staging ----
// 64x64 tile (MT=2,NT=2), K=2048 in 32 rounds of 64; 12 MFMAs/barrier-pair.
__global__ __launch_bounds__(256) void gemm_pv(
    const u16* __restrict__ sc, const u16* __restrict__ vT,
    u16* __restrict__ ao, int b0) {
  __shared__ u16 Alds[64 * 64];   // 8 KB
  __shared__ u16 Blds[64 * 64];   // 8 KB
  const int t = threadIdx.x;
  const int wave = t >> 6, lane = t & 63;
  const int rr = lane & 15, kq = lane >> 4;
  const int bz = blockIdx.z, bl = bz >> 4, h = bz & 15;
  const int b = b0 + bl;
  const int mB = blockIdx.y * 64;
  const u16* A = sc + (size_t)bz * 256 * 2048 + (size_t)mB * 2048;
  const u16* Bm = vT + (size_t)(b * 16 + h) * 64 * 2048;

  const u16* ag[2]; u16* al[2];
  const u16* bg[2]; u16* blp[2];
#pragma unroll
  for (int i = 0; i < 2; ++i) {
    int s = i * 256 + t;
    ag[i] = A + (size_t)(s >> 3) * 2048 + (s & 7) * 8;
    al[i] = Alds + (size_t)(i * 256 + wave * 64) * 8;
    bg[i] = Bm + (size_t)(s >> 3) * 2048 + (s & 7) * 8;
    blp[i] = Blds + (size_t)(i * 256 + wave * 64) * 8;
  }

  const int m0w = (wave & 1) * 32, n0w = (wave >> 1) * 32;
  // constant ones B-frag: virtual row n=0 all-ones -> l in acc col 0
  const short ov = (rr == 0) ? (short)0x3F80 : (short)0;
  const short8 ones = {ov, ov, ov, ov, ov, ov, ov, ov};

  const floatx4 zz = {0.f, 0.f, 0.f, 0.f};
  floatx4 acc[2][2] = {{zz, zz}, {zz, zz}};
  floatx4 acc_l[2] = {zz, zz};

  for (int k0 = 0; k0 < 2048; k0 += 64) {
#pragma unroll
    for (int i = 0; i < 2; ++i) gload16(ag[i] + k0, al[i]);
#pragma unroll
    for (int i = 0; i < 2; ++i) gload16(bg[i] + k0, blp[i]);
    __syncthreads();
#pragma unroll
    for (int ki = 0; ki < 2; ++ki) {
      short8 af[2], bfr[2];
#pragma unroll
      for (int mi = 0; mi < 2; ++mi)
        af[mi] = *reinterpret_cast<const short8*>(
            Alds + (size_t)(m0w + mi * 16 + rr) * 64 + ki * 32 + kq * 8);
#pragma unroll
      for (int ni = 0; ni < 2; ++ni)
        bfr[ni] = *reinterpret_cast<const short8*>(
            Blds + (size_t)(n0w + ni * 16 + rr) * 64 + ki * 32 + kq * 8);
#pragma unroll
      for (int mi = 0; mi < 2; ++mi) {
#pragma unroll
        for (int ni = 0; ni < 2; ++ni)
          acc[mi][ni] = __builtin_amdgcn_mfma_f32_16x16x32_bf16(af[mi], bfr[ni], acc[mi][ni], 0, 0, 0);
        acc_l[mi] = __builtin_amdgcn_mfma_f32_16x16x32_bf16(af[mi], ones, acc_l[mi], 0, 0, 0);
      }
    }
    __syncthreads();
  }

  // epilogue: l broadcast from col-0 lanes (rr==0, same kq), normalize, store
#pragma unroll
  for (int mi = 0; mi < 2; ++mi)
#pragma unroll
    for (int r = 0; r < 4; ++r) {
      float l = __shfl(acc_l[mi][r], lane & 48, 64);
      float inv = 1.0f / l;
      int m = mB + m0w + mi * 16 + kq * 4 + r;
#pragma unroll
      for (int ni = 0; ni < 2; ++ni) {
        int n = n0w + ni * 16 + rr;   // d within head
        ao[(size_t)(b * 256 + m) * 1024 + h * 64 + n] = f2bf(acc[mi][ni][r] * inv);
      }
    }
}

// ---- out-proj: out = ao @ w_out^T + b_out + queries (fp32), 64x128 tiles ----
__global__ __launch_bounds__(256) void gemm_out(
    const u16* __restrict__ A, const u16* __restrict__ W,
    const float* __restrict__ bias, const float* __restrict__ resid,
    float* __restrict__ out) {
  __shared__ u16 Alds[64 * 32];
  __shared__ u16 Blds[128 * 32];
  const int mB = blockIdx.y * 64;
  const int nB = blockIdx.x * 128;
  const floatx4 zz = {0.f, 0.f, 0.f, 0.f};
  floatx4 acc[2][4] = {{zz, zz, zz, zz}, {zz, zz, zz, zz}};
  gemm_core<2, 4>(A + (size_t)mB * 1024, 1024, W + (size_t)nB * 1024, 1024, 1024,
                  Alds, Blds, acc);
  const int lane = threadIdx.x & 63, wave = threadIdx.x >> 6;
  const int rr = lane & 15, r4 = (lane >> 4) * 4;
  const int m0w = (wave & 1) * 32, n0w = (wave >> 1) * 64;
#pragma unroll
  for (int mi = 0; mi < 2; ++mi)
#pragma unroll
    for (int ni = 0; ni < 4; ++ni) {
      int n = nB + n0w + ni * 16 + rr;
      float bv = bias[n];
#pragma unroll
      for (int r = 0; r < 4; ++r) {
        int m = mB + m0w + mi * 16 + r4 + r;
        size_t idx = (size_t)m * 1024 + n;
        out[idx] = acc[mi][ni][r] + bv + resid[idx];
      }
    }
}

extern "C" void kernel_launch(void* const* d_in, const int* in_sizes, int n_in,
                              void* d_out, int out_size, void* d_ws, size_t ws_size,
                              hipStream_t stream) {
  const float* sources = (const float*)d_in[0];  // [8,2048,1024]
  const float* queries = (const float*)d_in[1];  // [8,256,1024]
  const float* w_in    = (const float*)d_in[2];  // [3072,1024]
  const float* b_in    = (const float*)d_in[3];  // [3072]
  const float* w_out   = (const float*)d_in[4];  // [1024,1024]
  const float* b_out   = (const float*)d_in[5];  // [1024]
  float* out = (float*)d_out;                    // [8,256,1024] fp32

  char* ws = (char*)d_ws;
  size_t off = 0;
  auto alloc = [&](size_t bytes) -> char* {
    char* p = ws + off;
    off += bytes;
    off = (off + 255) & ~(size_t)255;
    return p;
  };
  // ---- live through attention (74 MB) ----
  u16* wo_bf = (u16*)alloc((size_t)1048576 * 2);   // w_out bf16
  u16* qp    = (u16*)alloc((size_t)2097152 * 2);   // projected q (pre-scaled 1/8)
  u16* kp    = (u16*)alloc((size_t)16777216 * 2);  // projected k
  u16* vT    = (u16*)alloc((size_t)16777216 * 2);  // projected v, [bh][d][n]
  u16* ao    = (u16*)alloc((size_t)2097152 * 2);   // attention output
  const size_t offA = off;                         // sc starts here (overlaps below)
  // ---- dead after proj (42 MB) — sc may overlap these ----
  u16* s_bf  = (u16*)alloc((size_t)16777216 * 2);  // sources bf16
  u16* qy_bf = (u16*)alloc((size_t)2097152 * 2);   // queries bf16
  u16* wi_bf = (u16*)alloc((size_t)3145728 * 2);   // w_in bf16

  // P buffer: 16.8 MB per batch element; chunk over batch to fit ws - offA
  u16* sc = (u16*)(ws + offA);
  const size_t sc_bytes_per_b = (size_t)16 * 256 * 2048 * 2;
  size_t sc_space = ws_size > offA ? ws_size - offA : 0;
  int bchunk = (int)(sc_space / sc_bytes_per_b);
  if (bchunk > 8) bchunk = 8;
  if (bchunk < 1) bchunk = 1;

  // 1) casts (single kernel)
  f2bf_multi<<<dim3(22528), 256, 0, stream>>>(
      sources, s_bf, queries, qy_bf, w_in, wi_bf, w_out, wo_bf);

  // 2) unified QKV projection
  gemm_proj<<<dim3(16, 144), 256, 0, stream>>>(
      s_bf, qy_bf, wi_bf, b_in, kp, vT, qp);

  // 3) attention: P = exp(QK^T) materialized, then O = P V (+l) -- chunked
  for (int b0 = 0; b0 < 8; b0 += bchunk) {
    int nb = (8 - b0) < bchunk ? (8 - b0) : bchunk;
    gemm_scores_exp<<<dim3(16, 2, nb * 16), 256, 0, stream>>>(qp, kp, sc, b0);
    gemm_pv<<<dim3(1, 4, nb * 16), 256, 0, stream>>>(sc, vT, ao, b0);
  }

  // 4) out-proj + bias + residual
  gemm_out<<<dim3(8, 32), 256, 0, stream>>>(ao, wo_bf, b_out, queries, out);
}